// Round 10
// baseline (115.069 us; speedup 1.0000x reference)
//
#include <hip/hip_runtime.h>
#include <math.h>

// (B,C,H,W) = (64,512,28,28)
#define NC    512
#define CST   784          // H*W
#define SEG   32           // channels per wave-segment
#define NSEG  16           // waves per block
#define TPB   1024
#define NTILE 784          // 64-column tiles
#define NBLK  256          // 1 block per CU; blocks 0..15 take 4 tiles, rest 3
#define GSZ   25690112

// ws: [0,8) double acc; [8,12) int ticket — memset 16B each launch

__global__ __launch_bounds__(TPB) void k_fused(const float* __restrict__ x,
                                               const float* __restrict__ w,
                                               float* __restrict__ g,
                                               double* __restrict__ acc,
                                               int* __restrict__ ticket,
                                               float* __restrict__ out) {
    const int lane = threadIdx.x & 63;
    const int s    = threadIdx.x >> 6;          // wave id = channel segment
    const int k0   = s * SEG;

    __shared__ float wl[NC];                    // wl[511] = 0
    __shared__ float sA[2][NSEG][64];
    __shared__ float sB[2][NSEG][64];
    __shared__ float lpart[NSEG];

    if (threadIdx.x < NC)
        wl[threadIdx.x] = (threadIdx.x < NC - 1) ? w[threadIdx.x] : 0.f;
    __syncthreads();

    const int n = (blockIdx.x < NTILE - 3 * NBLK) ? 4 : 3;   // 16 blocks get 4
    float lacc = 0.f;
    float xr0[SEG + 1], xr1[SEG + 1];

    // ---- load tile into regs (33 independent loads; top row guarded) ----
#define LOADX(xr, tid) do {                                                   \
        const int p_  = (tid) * 64 + lane;                                    \
        const int b_  = p_ / CST;                                             \
        const size_t bas_ = (size_t)b_ * (NC * CST) + (p_ - b_ * CST);        \
        _Pragma("unroll")                                                     \
        for (int j = 0; j < SEG; ++j)                                         \
            xr[j] = x[bas_ + (size_t)(k0 + j) * CST];                         \
        xr[SEG] = (s < NSEG - 1) ? x[bas_ + (size_t)(k0 + SEG) * CST] : 0.f;  \
    } while (0)

    // ---- one pipeline stage: phaseA(cur) | barrier | prefetch(nxt) | phaseB ----
#define PROCESS(cur, nxt, it_) do {                                           \
        const int buf_ = (it_) & 1;                                           \
        float a_ = 0.f, bs_ = 0.f;                                            \
        _Pragma("unroll")                                                     \
        for (int j = 0; j < SEG; ++j) {                                       \
            const float wk_ = wl[k0 + j];                                     \
            a_  = fmaf(cur[j],     wk_, a_);                                  \
            bs_ = fmaf(cur[j + 1], wk_, bs_);                                 \
        }                                                                     \
        sA[buf_][s][lane] = a_;                                               \
        sB[buf_][s][lane] = bs_;                                              \
        _Pragma("unroll")   /* pin: values resident -> free; blocks remat */  \
        for (int j = 0; j <= SEG; ++j) asm volatile("" : "+v"(cur[j]));       \
        __syncthreads();                                                      \
        if ((it_) + 1 < n) LOADX(nxt, blockIdx.x + NBLK * ((it_) + 1));       \
        float r_ = 0.f;                                                       \
        _Pragma("unroll")                                                     \
        for (int t_ = 0; t_ < NSEG; ++t_)                                     \
            r_ += (t_ < s) ? sA[buf_][t_][lane] : sB[buf_][t_][lane];         \
        {                                                                     \
            const int p_  = (blockIdx.x + NBLK * (it_)) * 64 + lane;          \
            const int b_  = p_ / CST;                                         \
            const size_t bas_ = (size_t)b_ * (NC * CST) + (p_ - b_ * CST);    \
            _Pragma("unroll")                                                 \
            for (int j = 0; j < SEG; ++j) {                                   \
                g[bas_ + (size_t)(k0 + j) * CST] = r_;                        \
                const float d_ = r_ - cur[j];                                 \
                lacc = fmaf(d_, d_, lacc);                                    \
                r_ = fmaf(wl[k0 + j], cur[j] - cur[j + 1], r_);               \
            }                                                                 \
        }                                                                     \
    } while (0)

    LOADX(xr0, blockIdx.x);
    int it = 0;
    while (true) {
        PROCESS(xr0, xr1, it); if (++it >= n) break;
        PROCESS(xr1, xr0, it); if (++it >= n) break;
    }

    // ---- loss: wave reduce -> block reduce -> device atomic + ticket ----
    #pragma unroll
    for (int off = 32; off; off >>= 1) lacc += __shfl_down(lacc, off, 64);
    if (lane == 0) lpart[s] = lacc;
    __syncthreads();
    if (threadIdx.x == 0) {
        float t = 0.f;
        #pragma unroll
        for (int i = 0; i < NSEG; ++i) t += lpart[i];
        atomicAdd(acc, (double)t);               // device-scope
        __threadfence();
        const int my = atomicAdd(ticket, 1);
        if (my == NBLK - 1) {                    // all blocks' acc-adds complete
            const double tot = __hip_atomic_load(acc, __ATOMIC_ACQUIRE,
                                                 __HIP_MEMORY_SCOPE_AGENT);
            out[0] = (float)(sqrt(tot) * 0.0025);
        }
    }
}

extern "C" void kernel_launch(void* const* d_in, const int* in_sizes, int n_in,
                              void* d_out, int out_size, void* d_ws, size_t ws_size,
                              hipStream_t stream) {
    const float* x = (const float*)d_in[0];
    const float* w = (const float*)d_in[1];
    float* g = (float*)d_out;
    double* acc = (double*)d_ws;
    int* ticket = (int*)((char*)d_ws + 8);

    hipMemsetAsync(d_ws, 0, 16, stream);
    k_fused<<<dim3(NBLK), dim3(TPB), 0, stream>>>(x, w, g, acc, ticket, g + GSZ);
}

// Round 11
// 73.798 us; speedup vs baseline: 1.5593x; 1.5593x over previous
//
#include <hip/hip_runtime.h>
#include <math.h>

// (B,C,H,W) = (64,512,28,28)
#define NC    512
#define CST   784          // H*W
#define SEG   64           // channels per wave-segment
#define NSEG  8            // waves per block
#define TPB   512
#define GSZ   25690112
#define NBLK  784          // 50176 columns / 64 lanes

// ws: [0,8) double acc; [8,12) int ticket — memset 16B each launch

__global__ __launch_bounds__(TPB) void k_fused(const float* __restrict__ x,
                                               const float* __restrict__ w,
                                               float* __restrict__ g,
                                               double* __restrict__ acc,
                                               int* __restrict__ ticket,
                                               float* __restrict__ out) {
    const int lane = threadIdx.x & 63;
    const int s    = threadIdx.x >> 6;          // wave id = channel segment
    const int p    = blockIdx.x * 64 + lane;    // column id
    const int b    = p / CST;
    const int hw   = p - b * CST;
    const size_t base = (size_t)b * (NC * CST) + hw;
    const float* xp = x + base;
    float*       gp = g + base;
    const int k0 = s * SEG;

    __shared__ float wl[NC];        // wl[511] = 0
    __shared__ float sA[NSEG][64];
    __shared__ float sB[NSEG][64];
    __shared__ float lpart[NSEG];

    wl[threadIdx.x] = (threadIdx.x < NC - 1) ? w[threadIdx.x] : 0.f;

    // ---- load this thread's 65-channel x slice ----
    float xr[SEG + 1];
    #pragma unroll
    for (int j = 0; j < SEG; ++j)
        xr[j] = xp[(size_t)(k0 + j) * CST];
    float xtop = 0.f;
    if (s < NSEG - 1) xtop = xp[(size_t)(k0 + SEG) * CST];   // wave-uniform guard
    xr[SEG] = xtop;

    __syncthreads();   // wl visible

    // ---- phase A: per-segment partial sums ----
    float a = 0.f, bs = 0.f;
    #pragma unroll
    for (int j = 0; j < SEG; ++j) {
        const float wk = wl[k0 + j];
        a  = fmaf(xr[j],     wk, a);          // A[k] = x[k]  * w[k]
        bs = fmaf(xr[j + 1], wk, bs);         // B[k] = x[k+1]* w[k]
    }
    sA[s][lane] = a;
    sB[s][lane] = bs;
    __syncthreads();

    // ---- g[k0] = sum_{t<s} A_t + sum_{t>=s} B_t ----
    float r = 0.f;
    #pragma unroll
    for (int t = 0; t < NSEG; ++t)
        r += (t < s) ? sA[t][lane] : sB[t][lane];

    // ---- phase B: emit g + loss ----
    float ls = 0.f;
    #pragma unroll
    for (int j = 0; j < SEG; ++j) {
        gp[(size_t)(k0 + j) * CST] = r;
        const float d = r - xr[j];
        ls = fmaf(d, d, ls);
        r = fmaf(wl[k0 + j], xr[j] - xr[j + 1], r);   // wl[511]=0 ⇒ safe at k=511
    }

    // ---- loss: wave reduce -> block reduce -> device atomic + ticket ----
    #pragma unroll
    for (int off = 32; off; off >>= 1) ls += __shfl_down(ls, off, 64);
    if (lane == 0) lpart[s] = ls;
    __syncthreads();
    if (threadIdx.x == 0) {
        float t = 0.f;
        #pragma unroll
        for (int i = 0; i < NSEG; ++i) t += lpart[i];
        atomicAdd(acc, (double)t);               // device-scope
        __threadfence();
        const int my = atomicAdd(ticket, 1);
        if (my == NBLK - 1) {                    // all blocks' acc-adds complete
            const double tot = __hip_atomic_load(acc, __ATOMIC_ACQUIRE,
                                                 __HIP_MEMORY_SCOPE_AGENT);
            out[0] = (float)(sqrt(tot) * 0.0025);
        }
    }
}

extern "C" void kernel_launch(void* const* d_in, const int* in_sizes, int n_in,
                              void* d_out, int out_size, void* d_ws, size_t ws_size,
                              hipStream_t stream) {
    const float* x = (const float*)d_in[0];
    const float* w = (const float*)d_in[1];
    float* g = (float*)d_out;
    double* acc = (double*)d_ws;
    int* ticket = (int*)((char*)d_ws + 8);

    hipMemsetAsync(d_ws, 0, 16, stream);
    k_fused<<<dim3(NBLK), dim3(TPB), 0, stream>>>(x, w, g, acc, ticket, g + GSZ);
}

// Round 12
// 47.890 us; speedup vs baseline: 2.4028x; 1.5410x over previous
//
#include <hip/hip_runtime.h>
#include <math.h>

// (B,C,H,W) = (64,512,28,28)
#define NC    512
#define CST   784          // H*W
#define SEG   32           // channels per wave-segment
#define NSEG  16           // waves per block
#define TPB   1024
#define GSZ   25690112
#define NBLK  784          // 50176 columns / 64 lanes

// ws: float part[NBLK] loss partials (rewritten every launch before k_final)

__global__ __launch_bounds__(TPB, 2) void k_fused(const float* __restrict__ x,
                                                  const float* __restrict__ w,
                                                  float* __restrict__ g,
                                                  float* __restrict__ part) {
    const int lane = threadIdx.x & 63;
    const int s    = threadIdx.x >> 6;          // wave id = channel segment
    const int p    = blockIdx.x * 64 + lane;    // column id
    const int b    = p / CST;
    const int hw   = p - b * CST;
    const size_t base = (size_t)b * (NC * CST) + hw;
    const float* xp = x + base;
    float*       gp = g + base;
    const int k0 = s * SEG;

    __shared__ float wl[NC];        // wl[511] = 0
    __shared__ float sA[NSEG][64];
    __shared__ float sB[NSEG][64];
    __shared__ float lpart[NSEG];

    if (threadIdx.x < NC)
        wl[threadIdx.x] = (threadIdx.x < NC - 1) ? w[threadIdx.x] : 0.f;
    __syncthreads();   // wl visible before phase A

    // top boundary value (channel k0+SEG), zero for the last segment
    float xtop = 0.f;
    if (s < NSEG - 1) xtop = xp[(size_t)(k0 + SEG) * CST];   // wave-uniform guard

    // ---- phase A: stream x once; build d[] in regs + loss-side sums ----
    // pa = local prefix of a[k]=x[k]w[k]; pb = local prefix of b2[k]=x[k+1]w[k]
    // LPa = sum x[k]*(pa-pb);  SX = sum x;  SXX = sum x^2
    float d[SEG];                   // d[j] = w[k](x[k]-x[k+1]) — NOT remat-able
    float pa = 0.f, pb = 0.f, SX = 0.f, SXX = 0.f, LPa = 0.f;
    float xv = xp[(size_t)k0 * CST];

#define BODY(j, xn_) do {                                     \
        const float xn = (xn_);                               \
        const float wk = wl[k0 + (j)];                        \
        SX  += xv;                                            \
        SXX  = fmaf(xv, xv, SXX);                             \
        LPa  = fmaf(xv, pa - pb, LPa);                        \
        pa   = fmaf(xv, wk, pa);                              \
        pb   = fmaf(xn, wk, pb);                              \
        d[j] = wk * (xv - xn);                                \
        xv = xn;                                              \
    } while (0)

    #pragma unroll
    for (int j = 0; j < SEG - 1; ++j)
        BODY(j, xp[(size_t)(k0 + j + 1) * CST]);
    BODY(SEG - 1, xtop);
#undef BODY

    sA[s][lane] = pa;               // A_s
    sB[s][lane] = pb;               // B_s
    __syncthreads();

    // ---- r0 = g[k0] = sum_{t<s} A_t + sum_{t>=s} B_t ----
    float r0 = 0.f;
    #pragma unroll
    for (int t = 0; t < NSEG; ++t)
        r0 += (t < s) ? sA[t][lane] : sB[t][lane];

    // loss pieces known already: sum_seg g*x = LPa + r0*SX
    float ls = fmaf(-2.f, fmaf(r0, SX, LPa), SXX);   // SXX - 2*sum(g x)

    // ---- phase B: zero loads — store r, accumulate sum g^2, step by d ----
    float r = r0, gs = 0.f;
    #pragma unroll
    for (int j = 0; j < SEG; ++j) {
        gp[(size_t)(k0 + j) * CST] = r;
        gs = fmaf(r, r, gs);
        r += d[j];
    }
    ls += gs;                       // = sum_seg (g-x)^2, algebraically

    // ---- loss: wave reduce -> block reduce -> one float per block ----
    #pragma unroll
    for (int off = 32; off; off >>= 1) ls += __shfl_down(ls, off, 64);
    if (lane == 0) lpart[s] = ls;
    __syncthreads();
    if (threadIdx.x == 0) {
        float t = 0.f;
        #pragma unroll
        for (int i = 0; i < NSEG; ++i) t += lpart[i];
        part[blockIdx.x] = t;
    }
}

__global__ __launch_bounds__(256) void k_final(const float* __restrict__ part,
                                               float* __restrict__ out) {
    double s = 0.0;
    for (int i = threadIdx.x; i < NBLK; i += 256) s += (double)part[i];
    #pragma unroll
    for (int off = 32; off; off >>= 1) s += __shfl_down(s, off, 64);
    __shared__ double sm[4];
    if ((threadIdx.x & 63) == 0) sm[threadIdx.x >> 6] = s;
    __syncthreads();
    if (threadIdx.x == 0)
        out[0] = (float)(sqrt(sm[0] + sm[1] + sm[2] + sm[3]) * 0.0025);
}

extern "C" void kernel_launch(void* const* d_in, const int* in_sizes, int n_in,
                              void* d_out, int out_size, void* d_ws, size_t ws_size,
                              hipStream_t stream) {
    const float* x = (const float*)d_in[0];
    const float* w = (const float*)d_in[1];
    float* g = (float*)d_out;
    float* part = (float*)d_ws;

    k_fused<<<dim3(NBLK), dim3(TPB), 0, stream>>>(x, w, g, part);
    k_final<<<1, 256, 0, stream>>>(part, g + GSZ);
}